// Round 1
// baseline (374.833 us; speedup 1.0000x reference)
//
#include <hip/hip_runtime.h>
#include <hip/hip_bf16.h>
#include <float.h>

#define B 4
#define L 1024
#define H 768
#define HEADS 12
#define E 22
#define MPD 128
#define EMB 512
#define M (B*MPD)      // 512 mentions
#define NE (B*E)       // 88 entities

// ---------------------------------------------------------------------------
// K1: per-entity logsumexp over gathered sequence rows -> e_cg (NE x H)
//     (writes entity_emb; this also initializes e_cg for K3's atomics)
// ---------------------------------------------------------------------------
__global__ __launch_bounds__(256) void k_entity_emb(
    const float* __restrict__ seq, const int* __restrict__ m_batch,
    const int* __restrict__ m_pos, const int* __restrict__ m_ent,
    float* __restrict__ e_cg)
{
    const int e = blockIdx.x;
    const int t = threadIdx.x;
    __shared__ int s_idx[MPD];
    __shared__ int s_cnt;
    if (t == 0) s_cnt = 0;
    __syncthreads();
    for (int m = t; m < M; m += 256)
        if (m_ent[m] == e) { int p = atomicAdd(&s_cnt, 1); s_idx[p] = m; }
    __syncthreads();
    const int cnt = s_cnt;
    __shared__ size_t s_off[MPD];
    for (int i = t; i < cnt; i += 256) {
        int m = s_idx[i];
        s_off[i] = ((size_t)m_batch[m] * L + m_pos[m]) * H;
    }
    __syncthreads();

    float mx0 = -FLT_MAX, mx1 = -FLT_MAX, mx2 = -FLT_MAX;
    for (int i = 0; i < cnt; ++i) {
        const float* r = seq + s_off[i];
        mx0 = fmaxf(mx0, r[t]);
        mx1 = fmaxf(mx1, r[t + 256]);
        mx2 = fmaxf(mx2, r[t + 512]);
    }
    float s0 = 0.f, s1 = 0.f, s2 = 0.f;
    for (int i = 0; i < cnt; ++i) {
        const float* r = seq + s_off[i];
        s0 += expf(r[t]       - mx0);
        s1 += expf(r[t + 256] - mx1);
        s2 += expf(r[t + 512] - mx2);
    }
    float o0, o1, o2;
    if (cnt > 0) {
        o0 = logf(s0 + 1e-30f) + mx0;
        o1 = logf(s1 + 1e-30f) + mx1;
        o2 = logf(s2 + 1e-30f) + mx2;
    } else { o0 = o1 = o2 = 0.f; }
    float* dst = e_cg + (size_t)e * H;
    dst[t] = o0; dst[t + 256] = o1; dst[t + 512] = o2;
}

// ---------------------------------------------------------------------------
// K2: e_att (NE x L): sum gathered attention rows over mentions x heads,
//     then the reference's exact normalization chain.
// ---------------------------------------------------------------------------
__global__ __launch_bounds__(1024) void k_eatt(
    const float* __restrict__ att, const int* __restrict__ m_batch,
    const int* __restrict__ m_pos, const int* __restrict__ m_ent,
    float* __restrict__ e_att)
{
    const int e = blockIdx.x;
    const int t = threadIdx.x;  // = l
    __shared__ int s_idx[MPD];
    __shared__ int s_cnt;
    if (t == 0) s_cnt = 0;
    __syncthreads();
    for (int m = t; m < M; m += 1024)
        if (m_ent[m] == e) { int p = atomicAdd(&s_cnt, 1); s_idx[p] = m; }
    __syncthreads();
    const int cnt = s_cnt;
    __shared__ size_t s_base[MPD];
    for (int i = t; i < cnt; i += 1024) {
        int m = s_idx[i];
        // attention[b, hd, pos, l] = ((b*HEADS + hd)*L + pos)*L + l
        s_base[i] = (size_t)m_batch[m] * HEADS * L * L + (size_t)m_pos[m] * L;
    }
    __syncthreads();

    float acc = 0.f;
    for (int i = 0; i < cnt; ++i) {
        const size_t base = s_base[i] + t;
        #pragma unroll
        for (int hd = 0; hd < HEADS; ++hd)
            acc += att[base + (size_t)hd * ((size_t)L * L)];
    }
    const float denom = ((float)cnt + 1e-5f) * (float)HEADS;
    const float a1 = acc / denom;

    // block reduction over 1024 threads (16 waves)
    float v = a1;
    #pragma unroll
    for (int off = 32; off > 0; off >>= 1) v += __shfl_xor(v, off, 64);
    __shared__ float s_part[16];
    const int wid = t >> 6, lane = t & 63;
    if (lane == 0) s_part[wid] = v;
    __syncthreads();
    __shared__ float s_total;
    if (t == 0) {
        float tot = 0.f;
        #pragma unroll
        for (int w = 0; w < 16; ++w) tot += s_part[w];
        s_total = tot + 1e-5f;
    }
    __syncthreads();
    e_att[(size_t)e * L + t] = a1 / s_total;
}

// ---------------------------------------------------------------------------
// K3: e_context[b,e,h] = sum_l e_att[b,e,l] * seq[b,l,h], atomicAdd into e_cg
// grid (H/128, L/128, B), block 128 (one h per thread, 128-l chunk)
// ---------------------------------------------------------------------------
__global__ __launch_bounds__(128) void k_econtext(
    const float* __restrict__ seq, const float* __restrict__ e_att,
    float* __restrict__ e_cg)
{
    const int b  = blockIdx.z;
    const int h  = blockIdx.x * 128 + threadIdx.x;
    const int l0 = blockIdx.y * 128;
    __shared__ float s_att[E][128];
    for (int i = threadIdx.x; i < E * 128; i += 128) {
        int el = i >> 7, dl = i & 127;
        s_att[el][dl] = e_att[(size_t)(b * E + el) * L + l0 + dl];
    }
    __syncthreads();
    float acc[E];
    #pragma unroll
    for (int e = 0; e < E; ++e) acc[e] = 0.f;
    const float* sp = seq + ((size_t)b * L + l0) * H + h;
    #pragma unroll 4
    for (int dl = 0; dl < 128; ++dl) {
        float s = sp[(size_t)dl * H];
        #pragma unroll
        for (int e = 0; e < E; ++e) acc[e] += s_att[e][dl] * s;
    }
    float* dst = e_cg + (size_t)(b * E) * H + h;
    #pragma unroll
    for (int e = 0; e < E; ++e) atomicAdd(dst + (size_t)e * H, acc[e]);
}

// ---------------------------------------------------------------------------
// K4: out[row, c] = tanh(dot(e_cg[row, :], w[:, c]) + bias[c])
// grid NE, block 512 (one EMB column per thread)
// ---------------------------------------------------------------------------
__global__ __launch_bounds__(512) void k_out(
    const float* __restrict__ e_cg, const float* __restrict__ w,
    const float* __restrict__ bias, float* __restrict__ out)
{
    const int row = blockIdx.x;
    const int c = threadIdx.x;
    __shared__ float s_row[H];
    for (int i = c; i < H; i += 512) s_row[i] = e_cg[(size_t)row * H + i];
    __syncthreads();
    float acc = bias[c];
    #pragma unroll 4
    for (int h = 0; h < H; ++h)
        acc += s_row[h] * w[(size_t)h * EMB + c];
    out[(size_t)row * EMB + c] = tanhf(acc);
}

extern "C" void kernel_launch(void* const* d_in, const int* in_sizes, int n_in,
                              void* d_out, int out_size, void* d_ws, size_t ws_size,
                              hipStream_t stream) {
    const float* seq   = (const float*)d_in[0];
    const float* att   = (const float*)d_in[1];
    const float* w     = (const float*)d_in[2];
    const float* bias  = (const float*)d_in[3];
    const int* m_batch = (const int*)d_in[4];
    const int* m_pos   = (const int*)d_in[5];
    const int* m_ent   = (const int*)d_in[6];
    float* out = (float*)d_out;

    float* ws    = (float*)d_ws;
    float* e_att = ws;                      // NE*L floats
    float* e_cg  = ws + (size_t)NE * L;     // NE*H floats

    k_entity_emb<<<NE, 256, 0, stream>>>(seq, m_batch, m_pos, m_ent, e_cg);
    k_eatt<<<NE, 1024, 0, stream>>>(att, m_batch, m_pos, m_ent, e_att);
    dim3 g3(H / 128, L / 128, B);
    k_econtext<<<g3, 128, 0, stream>>>(seq, e_att, e_cg);
    k_out<<<NE, 512, 0, stream>>>(e_cg, w, bias, out);
}

// Round 4
// 320.010 us; speedup vs baseline: 1.1713x; 1.1713x over previous
//
#include <hip/hip_runtime.h>
#include <hip/hip_bf16.h>
#include <float.h>

#define B 4
#define L 1024
#define H 768
#define HEADS 12
#define E 22
#define MPD 128
#define EMB 512
#define M (B*MPD)      // 512 mentions
#define NE (B*E)       // 88 entities
#define LCH_A 4        // l-chunks per entity in k_gather (256 l each)
#define LCH_B 16       // l-chunks in k_context (64 l each)
#define LB (L/LCH_B)   // 64

// ---------------------------------------------------------------------------
// K_A: fused gather stage, 256 threads/block.
//   blocks [0, NE*LCH_A): raw attention segment-sum for (entity e, l-chunk)
//       e_att_raw[e, l] = sum_{m in e} sum_hd att[b(m), hd, pos(m), l]
//       zpart[block]    = sum over this chunk's l of the above (wave-reduced)
//       cntf[e]         = mention count (written by chunk 0)
//   blocks [NE*LCH_A, NE*LCH_A+NE): per-entity logsumexp of gathered seq rows
//       -> written straight into e_cg (initializes it for K_B's atomics)
// ---------------------------------------------------------------------------
__global__ __launch_bounds__(256) void k_gather(
    const float* __restrict__ seq, const float* __restrict__ att,
    const int* __restrict__ m_batch, const int* __restrict__ m_pos,
    const int* __restrict__ m_ent,
    float* __restrict__ e_att_raw, float* __restrict__ e_cg,
    float* __restrict__ zpart, float* __restrict__ cntf)
{
    const int bx = blockIdx.x;
    const int t  = threadIdx.x;
    __shared__ int s_cnt;
    __shared__ size_t s_off[MPD];
    __shared__ float s_p[4];
    if (t == 0) s_cnt = 0;
    __syncthreads();

    if (bx < NE * LCH_A) {
        const int e = bx >> 2, chunk = bx & 3;
        for (int m = t; m < M; m += 256)
            if (m_ent[m] == e) {
                int p = atomicAdd(&s_cnt, 1);
                s_off[p] = (size_t)m_batch[m] * HEADS * L * L + (size_t)m_pos[m] * L;
            }
        __syncthreads();
        const int cnt = s_cnt;
        const int l = chunk * 256 + t;
        float acc = 0.f;
        for (int i = 0; i < cnt; ++i) {
            const float* p = att + s_off[i] + l;
            #pragma unroll
            for (int hd = 0; hd < HEADS; ++hd)
                acc += p[(size_t)hd * L * L];
        }
        e_att_raw[(size_t)e * L + l] = acc;
        // block reduce for Z partial
        float v = acc;
        #pragma unroll
        for (int off = 32; off > 0; off >>= 1) v += __shfl_xor(v, off, 64);
        if ((t & 63) == 0) s_p[t >> 6] = v;
        __syncthreads();
        if (t == 0) {
            zpart[bx] = s_p[0] + s_p[1] + s_p[2] + s_p[3];
            if (chunk == 0) cntf[e] = (float)cnt;
        }
    } else {
        const int e = bx - NE * LCH_A;
        for (int m = t; m < M; m += 256)
            if (m_ent[m] == e) {
                int p = atomicAdd(&s_cnt, 1);
                s_off[p] = ((size_t)m_batch[m] * L + m_pos[m]) * H;
            }
        __syncthreads();
        const int cnt = s_cnt;
        float mx0 = -FLT_MAX, mx1 = -FLT_MAX, mx2 = -FLT_MAX;
        for (int i = 0; i < cnt; ++i) {
            const float* r = seq + s_off[i];
            mx0 = fmaxf(mx0, r[t]);
            mx1 = fmaxf(mx1, r[t + 256]);
            mx2 = fmaxf(mx2, r[t + 512]);
        }
        float s0 = 0.f, s1 = 0.f, s2 = 0.f;
        for (int i = 0; i < cnt; ++i) {
            const float* r = seq + s_off[i];
            s0 += expf(r[t]       - mx0);
            s1 += expf(r[t + 256] - mx1);
            s2 += expf(r[t + 512] - mx2);
        }
        float o0, o1, o2;
        if (cnt > 0) {
            o0 = logf(s0 + 1e-30f) + mx0;
            o1 = logf(s1 + 1e-30f) + mx1;
            o2 = logf(s2 + 1e-30f) + mx2;
        } else { o0 = o1 = o2 = 0.f; }
        float* dst = e_cg + (size_t)e * H;
        dst[t] = o0; dst[t + 256] = o1; dst[t + 512] = o2;
    }
}

// ---------------------------------------------------------------------------
// K_B: e_context accumulation. grid (H/128, LCH_B, B), block 128.
//   acc[e] = sum_dl raw_att[e][dl] * seq[b, l0+dl, h]; then
//   atomicAdd(e_cg[b,e,h], acc[e] * norm[e]) where
//   norm[e] = 1 / (Zraw[e] + 1e-5 * (cnt[e]+1e-5)*HEADS)
//   (exactly equals the reference's /(cnt+1e-5) /HEADS /(rowsum+1e-5) chain)
// ---------------------------------------------------------------------------
__global__ __launch_bounds__(128) void k_context(
    const float* __restrict__ seq, const float* __restrict__ e_att_raw,
    const float* __restrict__ zpart, const float* __restrict__ cntf,
    float* __restrict__ e_cg)
{
    const int ht = blockIdx.x;   // 0..5
    const int lc = blockIdx.y;   // 0..LCH_B-1
    const int b  = blockIdx.z;
    const int t  = threadIdx.x;
    const int h  = ht * 128 + t;
    const int l0 = lc * LB;
    __shared__ float s_att[E][LB];
    __shared__ float s_norm[E];
    for (int i = t; i < E * LB; i += 128) {
        int el = i / LB, dl = i % LB;
        s_att[el][dl] = e_att_raw[(size_t)(b * E + el) * L + l0 + dl];
    }
    if (t < E) {
        int ge = b * E + t;
        float z = zpart[ge * LCH_A] + zpart[ge * LCH_A + 1]
                + zpart[ge * LCH_A + 2] + zpart[ge * LCH_A + 3];
        float c2 = (cntf[ge] + 1e-5f) * (float)HEADS;
        s_norm[t] = 1.f / (z + 1e-5f * c2);
    }
    __syncthreads();
    float acc[E];
    #pragma unroll
    for (int e = 0; e < E; ++e) acc[e] = 0.f;
    const float* sp = seq + ((size_t)b * L + l0) * H + h;
    #pragma unroll 4
    for (int dl = 0; dl < LB; ++dl) {
        float s = sp[(size_t)dl * H];
        #pragma unroll
        for (int e = 0; e < E; ++e) acc[e] += s_att[e][dl] * s;
    }
    float* dst = e_cg + (size_t)(b * E) * H + h;
    #pragma unroll
    for (int e = 0; e < E; ++e) atomicAdd(dst + (size_t)e * H, acc[e] * s_norm[e]);
}

// ---------------------------------------------------------------------------
// K_C: out[row, c] = tanh(dot(e_cg[row,:], w[:,c]) + bias[c])
// grid (NE, 4), block 128: each block does one row x 128-column quarter.
// ---------------------------------------------------------------------------
__global__ __launch_bounds__(128) void k_out(
    const float* __restrict__ e_cg, const float* __restrict__ w,
    const float* __restrict__ bias, float* __restrict__ out)
{
    const int row = blockIdx.x;
    const int c   = blockIdx.y * 128 + threadIdx.x;
    __shared__ float s_row[H];
    for (int i = threadIdx.x; i < H; i += 128) s_row[i] = e_cg[(size_t)row * H + i];
    __syncthreads();
    float acc = bias[c];
    #pragma unroll 8
    for (int h = 0; h < H; ++h)
        acc += s_row[h] * w[(size_t)h * EMB + c];
    out[(size_t)row * EMB + c] = tanhf(acc);
}

extern "C" void kernel_launch(void* const* d_in, const int* in_sizes, int n_in,
                              void* d_out, int out_size, void* d_ws, size_t ws_size,
                              hipStream_t stream) {
    const float* seq   = (const float*)d_in[0];
    const float* att   = (const float*)d_in[1];
    const float* w     = (const float*)d_in[2];
    const float* bias  = (const float*)d_in[3];
    const int* m_batch = (const int*)d_in[4];
    const int* m_pos   = (const int*)d_in[5];
    const int* m_ent   = (const int*)d_in[6];
    float* out = (float*)d_out;

    float* ws        = (float*)d_ws;
    float* e_att_raw = ws;                                   // NE*L   = 90112
    float* e_cg      = ws + (size_t)NE * L;                  // NE*H   = 67584
    float* zpart     = e_cg + (size_t)NE * H;                // NE*LCH_A = 352
    float* cntf      = zpart + NE * LCH_A;                   // NE     = 88

    k_gather<<<NE * LCH_A + NE, 256, 0, stream>>>(
        seq, att, m_batch, m_pos, m_ent, e_att_raw, e_cg, zpart, cntf);
    dim3 gB(H / 128, LCH_B, B);
    k_context<<<gB, 128, 0, stream>>>(seq, e_att_raw, zpart, cntf, e_cg);
    dim3 gC(NE, EMB / 128);
    k_out<<<gC, 128, 0, stream>>>(e_cg, w, bias, out);
}